// Round 6
// baseline (1186.326 us; speedup 1.0000x reference)
//
#include <hip/hip_runtime.h>
#include <hip/hip_bf16.h>
#include <cmath>

#define NSEQ 480
#define SEQN 128
#define CDIM 256
#define NH 8
#define HD 32
#define TOPM 20

typedef float f32x4 __attribute__((ext_vector_type(4)));
typedef short bf16x8 __attribute__((ext_vector_type(8)));

__device__ __forceinline__ unsigned short bf16_rn(float x) {
    unsigned int u = __float_as_uint(x);
    unsigned int r = (u + 0x7FFFu + ((u >> 16) & 1u)) >> 16;
    return (unsigned short)r;
}
__device__ __forceinline__ float bf16f(unsigned short h) {
    return __uint_as_float(((unsigned int)h) << 16);
}
__device__ __forceinline__ unsigned int okey(float v) {
    unsigned int u = __float_as_uint(v);
    return (u >> 31) ? ~u : (u | 0x80000000u);
}
__device__ __forceinline__ float okey_inv(unsigned int k) {
    return __uint_as_float((k >> 31) ? (k & 0x7FFFFFFFu) : ~k);
}
__device__ __forceinline__ unsigned pk_bf16(float a, float b) {
    union { __hip_bfloat162 h; unsigned u; } cv;
    cv.h = __float22bfloat162_rn(make_float2(a, b));
    return cv.u;
}
__device__ __forceinline__ void unpack_bf16x8(uint4 u, float* o) {
    o[0] = bf16f((unsigned short)(u.x & 0xffffu)); o[1] = bf16f((unsigned short)(u.x >> 16));
    o[2] = bf16f((unsigned short)(u.y & 0xffffu)); o[3] = bf16f((unsigned short)(u.y >> 16));
    o[4] = bf16f((unsigned short)(u.z & 0xffffu)); o[5] = bf16f((unsigned short)(u.z >> 16));
    o[6] = bf16f((unsigned short)(u.w & 0xffffu)); o[7] = bf16f((unsigned short)(u.w >> 16));
}

// ---------------------------------------------------------------------------
// K1: transpose (B, C, N) -> (B, N, C), add pos_embed, emit split-bf16 planes
__global__ __launch_bounds__(256) void prep_kernel(const float* __restrict__ RW,
                                                   const float* __restrict__ POS,
                                                   unsigned short* __restrict__ XH,
                                                   unsigned short* __restrict__ XL) {
    int b = blockIdx.x, n0 = blockIdx.y * 32, c0 = blockIdx.z * 32;
    __shared__ float tile[32][33];
    int tx = threadIdx.x & 31, ty = threadIdx.x >> 5;
#pragma unroll
    for (int jj = 0; jj < 4; ++jj) {
        int c = c0 + ty + 8 * jj;
        tile[ty + 8 * jj][tx] = RW[((size_t)b * CDIM + c) * SEQN + n0 + tx];
    }
    __syncthreads();
#pragma unroll
    for (int jj = 0; jj < 4; ++jj) {
        int n = n0 + ty + 8 * jj;
        int c = c0 + tx;
        float val = tile[tx][ty + 8 * jj] + POS[n * CDIM + c];
        unsigned short hi = bf16_rn(val);
        size_t idx = (size_t)b * SEQN * CDIM + n * CDIM + c;
        XH[idx] = hi;
        XL[idx] = bf16_rn(val - bf16f(hi));
    }
}

// ---------------------------------------------------------------------------
// K1b: both weight splits for one layer in one launch.
// grid (8, 32): y<24 -> qkv W (256x768), y>=24 -> proj W (256x256).
__global__ __launch_bounds__(256) void wsplit2_kernel(
    const float* __restrict__ Wq, const float* __restrict__ Wp,
    unsigned short* __restrict__ QH, unsigned short* __restrict__ QL,
    unsigned short* __restrict__ PH, unsigned short* __restrict__ PL) {
    int k0 = blockIdx.x * 32;
    int yy = blockIdx.y;
    const float* W;
    unsigned short *WH, *WL;
    int ncols, j0;
    if (yy < 24) { W = Wq; WH = QH; WL = QL; ncols = 768; j0 = yy * 32; }
    else         { W = Wp; WH = PH; WL = PL; ncols = 256; j0 = (yy - 24) * 32; }
    __shared__ float tile[32][33];
    int tx = threadIdx.x & 31, ty = threadIdx.x >> 5;
#pragma unroll
    for (int jj = 0; jj < 4; ++jj)
        tile[ty + 8 * jj][tx] = W[(size_t)(k0 + ty + 8 * jj) * ncols + j0 + tx];
    __syncthreads();
#pragma unroll
    for (int jj = 0; jj < 4; ++jj) {
        float v = tile[tx][ty + 8 * jj];
        unsigned short hi = bf16_rn(v);
        unsigned short lo = bf16_rn(v - bf16f(hi));
        size_t idx = (size_t)(j0 + ty + 8 * jj) * 256 + k0 + tx;
        WH[idx] = hi;
        WL[idx] = lo;
    }
}

// ---------------------------------------------------------------------------
// K2: fused qkv + exact top-20 attention.  512 threads / 8 waves, each wave
// owns 16 q-rows.  Q/K split-bf16 (3-term MFMA), V and P single-bf16.
// grid 3840, bid = (b&7) + 8h + 64(b>>3).  LDS = 40 KiB -> 4 blocks/CU,
// 32 waves/CU occupancy cap.
__global__ __launch_bounds__(512, 8) void attn_kernel(
    const unsigned short* __restrict__ XHi, const unsigned short* __restrict__ XLo,
    unsigned short* __restrict__ OH, unsigned short* __restrict__ OL,
    const unsigned short* __restrict__ WtHi, const unsigned short* __restrict__ WtLo,
    const float* __restrict__ BIAS) {
    const int bid = blockIdx.x;
    const int h = (bid >> 3) & 7;
    const int b = ((bid >> 6) << 3) | (bid & 7);
    const float scale = 0.17677669529663687f;  // 1/sqrt(32)

    // q/k: row-major [128][32], col swizzle d' = d ^ (((tok>>1)&3)<<3)
    // vT : [32][128],  col swizzle t' = t ^ ((d&7)<<3)
    __shared__ unsigned short qh[SEQN * HD], ql[SEQN * HD];
    __shared__ unsigned short kh[SEQN * HD], kl[SEQN * HD];
    __shared__ unsigned short vh[HD * SEQN];

    const int tid = threadIdx.x;
    const int w = tid >> 6;    // wave 0..7 -> token rows [w*16, w*16+16)
    const int l = tid & 63;
    const int l15 = l & 15;
    const int sct = l >> 4;
    const size_t xbase = (size_t)b * SEQN * CDIM;

    // ================= Phase 1: QKV via MFMA =================
    f32x4 acc[6];  // ni 0,1=q  2,3=k  4,5=v
#pragma unroll
    for (int ni = 0; ni < 6; ++ni) acc[ni] = (f32x4){0.f, 0.f, 0.f, 0.f};

#pragma unroll 2
    for (int ks = 0; ks < 8; ++ks) {
        const int kb = ks * 32;
        const int row = w * 16 + l15;
        size_t off = xbase + row * CDIM + kb + sct * 8;
        bf16x8 ahi = *reinterpret_cast<const bf16x8*>(XHi + off);
        bf16x8 alo = *reinterpret_cast<const bf16x8*>(XLo + off);
#pragma unroll
        for (int ni = 0; ni < 6; ++ni) {
            int j = ((ni >> 1) << 8) + h * HD + ((ni & 1) << 4) + l15;
            const int woff = j * 256 + kb + sct * 8;
            bf16x8 bh = *reinterpret_cast<const bf16x8*>(WtHi + woff);
            if (ni < 4) {
                bf16x8 bl = *reinterpret_cast<const bf16x8*>(WtLo + woff);
                acc[ni] = __builtin_amdgcn_mfma_f32_16x16x32_bf16(ahi, bh, acc[ni], 0, 0, 0);
                acc[ni] = __builtin_amdgcn_mfma_f32_16x16x32_bf16(ahi, bl, acc[ni], 0, 0, 0);
                acc[ni] = __builtin_amdgcn_mfma_f32_16x16x32_bf16(alo, bh, acc[ni], 0, 0, 0);
            } else {
                acc[ni] = __builtin_amdgcn_mfma_f32_16x16x32_bf16(ahi, bh, acc[ni], 0, 0, 0);
            }
        }
    }
    // epilogue: bias (+scale for q), split q/k, bf16 v
#pragma unroll
    for (int ni = 0; ni < 6; ++ni) {
        const int sel = ni >> 1;
        const int dcol = ((ni & 1) << 4) + l15;
        const float bias = BIAS[(sel << 8) + h * HD + dcol];
        const int tb = w * 16 + sct * 4;
        if (sel == 2) {
            float v0 = acc[ni][0] + bias, v1 = acc[ni][1] + bias;
            float v2 = acc[ni][2] + bias, v3 = acc[ni][3] + bias;
            unsigned pA = pk_bf16(v0, v1), pB = pk_bf16(v2, v3);
            int c0i = tb ^ ((dcol & 7) << 3);
            *reinterpret_cast<uint2*>(&vh[dcol * SEQN + c0i]) = make_uint2(pA, pB);
        } else {
            unsigned short* ph = sel ? kh : qh;
            unsigned short* pl = sel ? kl : ql;
#pragma unroll
            for (int r = 0; r < 4; ++r) {
                float v = acc[ni][r] + bias;
                if (sel == 0) v *= scale;
                unsigned short hi = bf16_rn(v);
                int token = tb + r;
                int idx = token * HD + (dcol ^ (((token >> 1) & 3) << 3));
                ph[idx] = hi;
                pl[idx] = bf16_rn(v - bf16f(hi));
            }
        }
    }
    __syncthreads();

    // ================= Phase 2: S^T = K·Q^T, in-register softmax ============
    f32x4 sacc[8];
#pragma unroll
    for (int mi = 0; mi < 8; ++mi) sacc[mi] = (f32x4){0.f, 0.f, 0.f, 0.f};

    const int qrow = w * 16 + l15;
    const int qoff = qrow * HD + ((sct * 8) ^ (((qrow >> 1) & 3) << 3));
    bf16x8 qfh = *reinterpret_cast<const bf16x8*>(qh + qoff);
    bf16x8 qfl = *reinterpret_cast<const bf16x8*>(ql + qoff);
    __builtin_amdgcn_s_setprio(1);
#pragma unroll
    for (int mi = 0; mi < 8; ++mi) {
        int krow = (mi << 4) + l15;
        int off = krow * HD + ((sct * 8) ^ (((krow >> 1) & 3) << 3));
        bf16x8 kfh = *reinterpret_cast<const bf16x8*>(kh + off);
        bf16x8 kfl = *reinterpret_cast<const bf16x8*>(kl + off);
        sacc[mi] = __builtin_amdgcn_mfma_f32_16x16x32_bf16(kfh, qfh, sacc[mi], 0, 0, 0);
        sacc[mi] = __builtin_amdgcn_mfma_f32_16x16x32_bf16(kfh, qfl, sacc[mi], 0, 0, 0);
        sacc[mi] = __builtin_amdgcn_mfma_f32_16x16x32_bf16(kfl, qfh, sacc[mi], 0, 0, 0);
    }
    __builtin_amdgcn_s_setprio(0);
    // convert to ordered keys in place
#pragma unroll
    for (int mi = 0; mi < 8; ++mi)
#pragma unroll
        for (int r = 0; r < 4; ++r)
            sacc[mi][r] = __uint_as_float(okey(sacc[mi][r]));

    // row max (monotone in key domain)
    unsigned int km = 0u;
#pragma unroll
    for (int mi = 0; mi < 8; ++mi)
#pragma unroll
        for (int r = 0; r < 4; ++r) km = max(km, __float_as_uint(sacc[mi][r]));
    km = max(km, (unsigned int)__shfl_xor((int)km, 16));
    km = max(km, (unsigned int)__shfl_xor((int)km, 32));
    float mx = okey_inv(km);

    // exact top-20 threshold: bracketed bisection, early exit at c==20
    unsigned p0;
    {
        unsigned lo = 0u, hi = km + 1u, th = km;
        int dn = 0;
#pragma unroll 1
        for (int it = 0; it < 34; ++it) {
            if (__all(dn)) break;
            unsigned mid = lo + ((hi - lo) >> 1);
            int c = 0;
#pragma unroll
            for (int mi = 0; mi < 8; ++mi)
#pragma unroll
                for (int r = 0; r < 4; ++r)
                    c += (__float_as_uint(sacc[mi][r]) >= mid) ? 1 : 0;
            c += __shfl_xor(c, 16);
            c += __shfl_xor(c, 32);
            if (!dn) {
                if (c == TOPM) { th = mid; dn = 1; }
                else if (hi - lo <= 1u) { th = lo; dn = 1; }
                else if (c > TOPM) lo = mid;
                else hi = mid;
            }
        }
        p0 = th;
    }

    // masked exp (unnormalized) + row sum
    float s0 = 0.f;
#pragma unroll
    for (int mi = 0; mi < 8; ++mi)
#pragma unroll
        for (int r = 0; r < 4; ++r) {
            unsigned int u0 = __float_as_uint(sacc[mi][r]);
            float e0 = (u0 >= p0) ? __expf(okey_inv(u0) - mx) : 0.f;
            sacc[mi][r] = e0;
            s0 += e0;
        }
    s0 += __shfl_xor(s0, 16);
    s0 += __shfl_xor(s0, 32);
    float i0 = 1.f / s0;

    // pack weights to bf16 pairs
    unsigned w16a[8][2];
#pragma unroll
    for (int mi = 0; mi < 8; ++mi)
#pragma unroll
        for (int p = 0; p < 2; ++p)
            w16a[mi][p] = pk_bf16(sacc[mi][2 * p], sacc[mi][2 * p + 1]);

    // ================= Phase 3: O = P·V via MFMA ==============
    f32x4 oacc[2];
#pragma unroll
    for (int ni = 0; ni < 2; ++ni) oacc[ni] = (f32x4){0.f, 0.f, 0.f, 0.f};

#pragma unroll
    for (int k = 0; k < 4; ++k) {
        bf16x8 bvh[2];
#pragma unroll
        for (int nio = 0; nio < 2; ++nio) {
            int drow = (nio << 4) + l15;
            int off = drow * SEQN + ((k * 32 + sct * 8) ^ ((drow & 7) << 3));
            bvh[nio] = *reinterpret_cast<const bf16x8*>(vh + off);
        }
        union { unsigned u[4]; bf16x8 v8; } aw;
#pragma unroll
        for (int j = 0; j < 4; ++j) {
            int src = l15 + ((sct & 1) << 5) + ((j >> 1) << 4);
            unsigned a0 = (unsigned)__shfl((int)w16a[2 * k][j & 1], src);
            unsigned a1 = (unsigned)__shfl((int)w16a[2 * k + 1][j & 1], src);
            aw.u[j] = (sct >= 2) ? a1 : a0;
        }
        __builtin_amdgcn_s_setprio(1);
#pragma unroll
        for (int nio = 0; nio < 2; ++nio)
            oacc[nio] = __builtin_amdgcn_mfma_f32_16x16x32_bf16(aw.v8, bvh[nio], oacc[nio], 0, 0, 0);
        __builtin_amdgcn_s_setprio(0);
    }
    float invO[4];
#pragma unroll
    for (int r = 0; r < 4; ++r) invO[r] = __shfl(i0, sct * 4 + r);
#pragma unroll
    for (int nio = 0; nio < 2; ++nio)
#pragma unroll
        for (int r = 0; r < 4; ++r) {
            int token = w * 16 + sct * 4 + r;
            int d = (nio << 4) + l15;
            size_t idx = ((size_t)b * SEQN + token) * CDIM + h * HD + d;
            float v = oacc[nio][r] * invO[r];
            unsigned short hi = bf16_rn(v);
            OH[idx] = hi;
            OL[idx] = bf16_rn(v - bf16f(hi));
        }
}

// ---------------------------------------------------------------------------
// K3: MFMA proj GEMM + bias + residual + LayerNorm, 32 tokens per block.
// grid (480, 4), block 256 (4 waves, each 32 tok x 64 cols).  LDS ~39 KB.
__global__ __launch_bounds__(256, 4) void projln_kernel(
    const unsigned short* __restrict__ OHp, const unsigned short* __restrict__ OLp,
    unsigned short* __restrict__ XH, unsigned short* __restrict__ XL,
    const unsigned short* __restrict__ W2H, const unsigned short* __restrict__ W2L,
    const float* __restrict__ PB, const float* __restrict__ G,
    const float* __restrict__ BB) {
    const int b = blockIdx.x;
    const int t0 = blockIdx.y * 32;
    __shared__ float vals[32 * 289];
    __shared__ float part[8][32][2];

    const int tid = threadIdx.x;
    const int w = tid >> 6;
    const int l = tid & 63;
    const int l15 = l & 15;
    const int sct = l >> 4;

    f32x4 acc[2][4];
#pragma unroll
    for (int mi = 0; mi < 2; ++mi)
#pragma unroll
        for (int ni = 0; ni < 4; ++ni) acc[mi][ni] = (f32x4){0.f, 0.f, 0.f, 0.f};

    const size_t obase = ((size_t)b * SEQN + t0) * CDIM;
#pragma unroll 2
    for (int ks = 0; ks < 8; ++ks) {
        const int kb = ks * 32;
        bf16x8 ahi[2], alo[2];
#pragma unroll
        for (int mi = 0; mi < 2; ++mi) {
            size_t off = obase + (size_t)(mi * 16 + l15) * CDIM + kb + sct * 8;
            ahi[mi] = *reinterpret_cast<const bf16x8*>(OHp + off);
            alo[mi] = *reinterpret_cast<const bf16x8*>(OLp + off);
        }
#pragma unroll
        for (int ni = 0; ni < 4; ++ni) {
            int j = w * 64 + ni * 16 + l15;
            int woff = j * 256 + kb + sct * 8;
            bf16x8 bh = *reinterpret_cast<const bf16x8*>(W2H + woff);
            bf16x8 bl = *reinterpret_cast<const bf16x8*>(W2L + woff);
#pragma unroll
            for (int mi = 0; mi < 2; ++mi) {
                acc[mi][ni] = __builtin_amdgcn_mfma_f32_16x16x32_bf16(ahi[mi], bh, acc[mi][ni], 0, 0, 0);
                acc[mi][ni] = __builtin_amdgcn_mfma_f32_16x16x32_bf16(ahi[mi], bl, acc[mi][ni], 0, 0, 0);
                acc[mi][ni] = __builtin_amdgcn_mfma_f32_16x16x32_bf16(alo[mi], bh, acc[mi][ni], 0, 0, 0);
            }
        }
    }
    // bias + stage to LDS (stride 289 -> conflict-free strided readback)
#pragma unroll
    for (int ni = 0; ni < 4; ++ni) {
        int j = w * 64 + ni * 16 + l15;
        float bias = PB[j];
#pragma unroll
        for (int mi = 0; mi < 2; ++mi)
#pragma unroll
            for (int r = 0; r < 4; ++r) {
                int tok = mi * 16 + sct * 4 + r;
                vals[tok * 289 + j] = acc[mi][ni][r] + bias;
            }
    }
    __syncthreads();

    // residual + stats: thread = (row 0..31, cc 0..7 chunks of 32 cols)
    const int row = tid & 31;
    const int cc = tid >> 5;
    const size_t rbase = ((size_t)b * SEQN + t0 + row) * CDIM + cc * 32;
    float v[32];
    {
        float ps = 0.f, pq = 0.f;
#pragma unroll
        for (int q = 0; q < 4; ++q) {
            uint4 hb = *reinterpret_cast<const uint4*>(XH + rbase + q * 8);
            uint4 lb = *reinterpret_cast<const uint4*>(XL + rbase + q * 8);
            float rh[8], rl[8];
            unpack_bf16x8(hb, rh);
            unpack_bf16x8(lb, rl);
#pragma unroll
            for (int jj = 0; jj < 8; ++jj) {
                int col = cc * 32 + q * 8 + jj;
                float val = vals[row * 289 + col] + rh[jj] + rl[jj];
                v[q * 8 + jj] = val;
                ps += val;
                pq = fmaf(val, val, pq);
            }
        }
        part[cc][row][0] = ps;
        part[cc][row][1] = pq;
    }
    __syncthreads();
    float s1 = 0.f, s2 = 0.f;
#pragma unroll
    for (int k = 0; k < 8; ++k) { s1 += part[k][row][0]; s2 += part[k][row][1]; }
    float m = s1 * (1.f / 256.f);
    float var = s2 * (1.f / 256.f) - m * m;
    float rstd = rsqrtf(var + 1e-5f);
#pragma unroll
    for (int q = 0; q < 4; ++q) {
        int col0 = cc * 32 + q * 8;
        float4 g0 = *reinterpret_cast<const float4*>(G + col0);
        float4 g1 = *reinterpret_cast<const float4*>(G + col0 + 4);
        float4 b0 = *reinterpret_cast<const float4*>(BB + col0);
        float4 b1 = *reinterpret_cast<const float4*>(BB + col0 + 4);
        float gg[8] = {g0.x, g0.y, g0.z, g0.w, g1.x, g1.y, g1.z, g1.w};
        float bb2[8] = {b0.x, b0.y, b0.z, b0.w, b1.x, b1.y, b1.z, b1.w};
        unsigned hw[4], lw[4];
#pragma unroll
        for (int p2 = 0; p2 < 4; ++p2) {
            float y0 = (v[q * 8 + p2 * 2] - m) * rstd * gg[p2 * 2] + bb2[p2 * 2];
            float y1 = (v[q * 8 + p2 * 2 + 1] - m) * rstd * gg[p2 * 2 + 1] + bb2[p2 * 2 + 1];
            unsigned short h0 = bf16_rn(y0), h1 = bf16_rn(y1);
            unsigned short lo0 = bf16_rn(y0 - bf16f(h0)), lo1 = bf16_rn(y1 - bf16f(h1));
            hw[p2] = (unsigned)h0 | ((unsigned)h1 << 16);
            lw[p2] = (unsigned)lo0 | ((unsigned)lo1 << 16);
        }
        *reinterpret_cast<uint4*>(XH + rbase + q * 8) = make_uint4(hw[0], hw[1], hw[2], hw[3]);
        *reinterpret_cast<uint4*>(XL + rbase + q * 8) = make_uint4(lw[0], lw[1], lw[2], lw[3]);
    }
}

// ---------------------------------------------------------------------------
// K4: mean over tokens + classifier head (reads planes). grid 480, block 256.
__global__ __launch_bounds__(256) void cls_kernel(const unsigned short* __restrict__ XH,
                                                  const unsigned short* __restrict__ XL,
                                                  const float* __restrict__ W1,
                                                  const float* __restrict__ B1,
                                                  const float* __restrict__ W2,
                                                  const float* __restrict__ B2,
                                                  float* __restrict__ OUT) {
    int b = blockIdx.x;
    __shared__ float xm[256];
    __shared__ float hred[128];
    int tid = threadIdx.x;
    float sm = 0.f;
    for (int n = 0; n < SEQN; ++n) {
        size_t idx = ((size_t)b * SEQN + n) * CDIM + tid;
        sm += bf16f(XH[idx]) + bf16f(XL[idx]);
    }
    xm[tid] = sm * (1.f / 128.f);
    __syncthreads();
    if (tid < 128) {
        float a = B1[tid];
        for (int k = 0; k < CDIM; ++k) a = fmaf(xm[k], W1[k * 128 + tid], a);
        a = fmaxf(a, 0.f);
        hred[tid] = a * W2[tid];
    }
    __syncthreads();
    for (int off = 64; off > 0; off >>= 1) {
        if (tid < off) hred[tid] += hred[tid + off];
        __syncthreads();
    }
    if (tid == 0) OUT[b] = hred[0] + B2[0];
}

// ---------------------------------------------------------------------------
extern "C" void kernel_launch(void* const* d_in, const int* in_sizes, int n_in,
                              void* d_out, int out_size, void* d_ws, size_t ws_size,
                              hipStream_t stream) {
    const float* RW  = (const float*)d_in[0];
    const float* POS = (const float*)d_in[1];
    const float* CW1 = (const float*)d_in[2];
    const float* CB1 = (const float*)d_in[3];
    const float* CW2 = (const float*)d_in[4];
    const float* CB2 = (const float*)d_in[5];

    const size_t NTOK = (size_t)NSEQ * SEQN * CDIM;  // 15.7M
    unsigned short* OH = (unsigned short*)d_ws;
    unsigned short* OL = OH + NTOK;
    unsigned short* XH = OL + NTOK;
    unsigned short* XL = XH + NTOK;
    unsigned short* WtHi = XL + NTOK;
    unsigned short* WtLo = WtHi + (size_t)768 * 256;
    unsigned short* W2H = WtLo + (size_t)768 * 256;
    unsigned short* W2L = W2H + (size_t)256 * 256;

    prep_kernel<<<dim3(NSEQ, 4, 8), 256, 0, stream>>>(RW, POS, XH, XL);

    for (int li = 0; li < 2; ++li) {
        const float* qw = (const float*)d_in[6 + 6 * li];
        const float* qb = (const float*)d_in[7 + 6 * li];
        const float* pw = (const float*)d_in[8 + 6 * li];
        const float* pb = (const float*)d_in[9 + 6 * li];
        const float* lg = (const float*)d_in[10 + 6 * li];
        const float* lb = (const float*)d_in[11 + 6 * li];
        wsplit2_kernel<<<dim3(8, 32), 256, 0, stream>>>(qw, pw, WtHi, WtLo, W2H, W2L);
        attn_kernel<<<NSEQ * NH, 512, 0, stream>>>(XH, XL, OH, OL, WtHi, WtLo, qb);
        projln_kernel<<<dim3(NSEQ, 4), 256, 0, stream>>>(OH, OL, XH, XL, W2H, W2L, pb, lg, lb);
    }

    cls_kernel<<<NSEQ, 256, 0, stream>>>(XH, XL, CW1, CB1, CW2, CB2, (float*)d_out);
}

// Round 7
// 1037.372 us; speedup vs baseline: 1.1436x; 1.1436x over previous
//
#include <hip/hip_runtime.h>
#include <hip/hip_bf16.h>
#include <cmath>

#define NSEQ 480
#define SEQN 128
#define CDIM 256
#define NH 8
#define HD 32
#define TOPM 20

typedef float f32x4 __attribute__((ext_vector_type(4)));
typedef short bf16x8 __attribute__((ext_vector_type(8)));

__device__ __forceinline__ unsigned short bf16_rn(float x) {
    unsigned int u = __float_as_uint(x);
    unsigned int r = (u + 0x7FFFu + ((u >> 16) & 1u)) >> 16;
    return (unsigned short)r;
}
__device__ __forceinline__ float bf16f(unsigned short h) {
    return __uint_as_float(((unsigned int)h) << 16);
}
__device__ __forceinline__ unsigned int okey(float v) {
    unsigned int u = __float_as_uint(v);
    return (u >> 31) ? ~u : (u | 0x80000000u);
}
__device__ __forceinline__ float okey_inv(unsigned int k) {
    return __uint_as_float((k >> 31) ? (k & 0x7FFFFFFFu) : ~k);
}
__device__ __forceinline__ unsigned pk_bf16(float a, float b) {
    union { __hip_bfloat162 h; unsigned u; } cv;
    cv.h = __float22bfloat162_rn(make_float2(a, b));
    return cv.u;
}
__device__ __forceinline__ void unpack_bf16x8(uint4 u, float* o) {
    o[0] = bf16f((unsigned short)(u.x & 0xffffu)); o[1] = bf16f((unsigned short)(u.x >> 16));
    o[2] = bf16f((unsigned short)(u.y & 0xffffu)); o[3] = bf16f((unsigned short)(u.y >> 16));
    o[4] = bf16f((unsigned short)(u.z & 0xffffu)); o[5] = bf16f((unsigned short)(u.z >> 16));
    o[6] = bf16f((unsigned short)(u.w & 0xffffu)); o[7] = bf16f((unsigned short)(u.w >> 16));
}

// ---------------------------------------------------------------------------
// K1: transpose (B, C, N) -> (B, N, C), add pos_embed, emit split-bf16 planes
__global__ __launch_bounds__(256) void prep_kernel(const float* __restrict__ RW,
                                                   const float* __restrict__ POS,
                                                   unsigned short* __restrict__ XH,
                                                   unsigned short* __restrict__ XL) {
    int b = blockIdx.x, n0 = blockIdx.y * 32, c0 = blockIdx.z * 32;
    __shared__ float tile[32][33];
    int tx = threadIdx.x & 31, ty = threadIdx.x >> 5;
#pragma unroll
    for (int jj = 0; jj < 4; ++jj) {
        int c = c0 + ty + 8 * jj;
        tile[ty + 8 * jj][tx] = RW[((size_t)b * CDIM + c) * SEQN + n0 + tx];
    }
    __syncthreads();
#pragma unroll
    for (int jj = 0; jj < 4; ++jj) {
        int n = n0 + ty + 8 * jj;
        int c = c0 + tx;
        float val = tile[tx][ty + 8 * jj] + POS[n * CDIM + c];
        unsigned short hi = bf16_rn(val);
        size_t idx = (size_t)b * SEQN * CDIM + n * CDIM + c;
        XH[idx] = hi;
        XL[idx] = bf16_rn(val - bf16f(hi));
    }
}

// ---------------------------------------------------------------------------
// K1b: both weight splits for one layer in one launch.
// grid (8, 32): y<24 -> qkv W (256x768), y>=24 -> proj W (256x256).
__global__ __launch_bounds__(256) void wsplit2_kernel(
    const float* __restrict__ Wq, const float* __restrict__ Wp,
    unsigned short* __restrict__ QH, unsigned short* __restrict__ QL,
    unsigned short* __restrict__ PH, unsigned short* __restrict__ PL) {
    int k0 = blockIdx.x * 32;
    int yy = blockIdx.y;
    const float* W;
    unsigned short *WH, *WL;
    int ncols, j0;
    if (yy < 24) { W = Wq; WH = QH; WL = QL; ncols = 768; j0 = yy * 32; }
    else         { W = Wp; WH = PH; WL = PL; ncols = 256; j0 = (yy - 24) * 32; }
    __shared__ float tile[32][33];
    int tx = threadIdx.x & 31, ty = threadIdx.x >> 5;
#pragma unroll
    for (int jj = 0; jj < 4; ++jj)
        tile[ty + 8 * jj][tx] = W[(size_t)(k0 + ty + 8 * jj) * ncols + j0 + tx];
    __syncthreads();
#pragma unroll
    for (int jj = 0; jj < 4; ++jj) {
        float v = tile[tx][ty + 8 * jj];
        unsigned short hi = bf16_rn(v);
        unsigned short lo = bf16_rn(v - bf16f(hi));
        size_t idx = (size_t)(j0 + ty + 8 * jj) * 256 + k0 + tx;
        WH[idx] = hi;
        WL[idx] = lo;
    }
}

// ---------------------------------------------------------------------------
// K2: fused qkv + exact top-20 attention.  512 threads / 8 waves, each wave
// owns 16 q-rows.  Q/K split-bf16 (3-term MFMA), V and P single-bf16.
// grid 3840, bid = (b&7) + 8h + 64(b>>3).  LDS = 40 KiB -> 4 blocks/CU.
// __launch_bounds__(512, 4): 4 blocks/CU * 8 waves = 32 waves/CU -> VGPR<=64
// (round-6's (512,8) forced VGPR=32 -> catastrophic scratch spill, FETCH 461MB).
__global__ __launch_bounds__(512, 4) void attn_kernel(
    const unsigned short* __restrict__ XHi, const unsigned short* __restrict__ XLo,
    unsigned short* __restrict__ OH, unsigned short* __restrict__ OL,
    const unsigned short* __restrict__ WtHi, const unsigned short* __restrict__ WtLo,
    const float* __restrict__ BIAS) {
    const int bid = blockIdx.x;
    const int h = (bid >> 3) & 7;
    const int b = ((bid >> 6) << 3) | (bid & 7);
    const float scale = 0.17677669529663687f;  // 1/sqrt(32)

    // q/k: row-major [128][32], col swizzle d' = d ^ (((tok>>1)&3)<<3)
    // vT : [32][128],  col swizzle t' = t ^ ((d&7)<<3)
    __shared__ unsigned short qh[SEQN * HD], ql[SEQN * HD];
    __shared__ unsigned short kh[SEQN * HD], kl[SEQN * HD];
    __shared__ unsigned short vh[HD * SEQN];

    const int tid = threadIdx.x;
    const int w = tid >> 6;    // wave 0..7 -> token rows [w*16, w*16+16)
    const int l = tid & 63;
    const int l15 = l & 15;
    const int sct = l >> 4;
    const size_t xbase = (size_t)b * SEQN * CDIM;

    // ================= Phase 1: QKV via MFMA =================
    f32x4 acc[6];  // ni 0,1=q  2,3=k  4,5=v
#pragma unroll
    for (int ni = 0; ni < 6; ++ni) acc[ni] = (f32x4){0.f, 0.f, 0.f, 0.f};

#pragma unroll 2
    for (int ks = 0; ks < 8; ++ks) {
        const int kb = ks * 32;
        const int row = w * 16 + l15;
        size_t off = xbase + row * CDIM + kb + sct * 8;
        bf16x8 ahi = *reinterpret_cast<const bf16x8*>(XHi + off);
        bf16x8 alo = *reinterpret_cast<const bf16x8*>(XLo + off);
#pragma unroll
        for (int ni = 0; ni < 6; ++ni) {
            int j = ((ni >> 1) << 8) + h * HD + ((ni & 1) << 4) + l15;
            const int woff = j * 256 + kb + sct * 8;
            bf16x8 bh = *reinterpret_cast<const bf16x8*>(WtHi + woff);
            if (ni < 4) {
                bf16x8 bl = *reinterpret_cast<const bf16x8*>(WtLo + woff);
                acc[ni] = __builtin_amdgcn_mfma_f32_16x16x32_bf16(ahi, bh, acc[ni], 0, 0, 0);
                acc[ni] = __builtin_amdgcn_mfma_f32_16x16x32_bf16(ahi, bl, acc[ni], 0, 0, 0);
                acc[ni] = __builtin_amdgcn_mfma_f32_16x16x32_bf16(alo, bh, acc[ni], 0, 0, 0);
            } else {
                acc[ni] = __builtin_amdgcn_mfma_f32_16x16x32_bf16(ahi, bh, acc[ni], 0, 0, 0);
            }
        }
    }
    // epilogue: bias (+scale for q), split q/k, bf16 v
#pragma unroll
    for (int ni = 0; ni < 6; ++ni) {
        const int sel = ni >> 1;
        const int dcol = ((ni & 1) << 4) + l15;
        const float bias = BIAS[(sel << 8) + h * HD + dcol];
        const int tb = w * 16 + sct * 4;
        if (sel == 2) {
            float v0 = acc[ni][0] + bias, v1 = acc[ni][1] + bias;
            float v2 = acc[ni][2] + bias, v3 = acc[ni][3] + bias;
            unsigned pA = pk_bf16(v0, v1), pB = pk_bf16(v2, v3);
            int c0i = tb ^ ((dcol & 7) << 3);
            *reinterpret_cast<uint2*>(&vh[dcol * SEQN + c0i]) = make_uint2(pA, pB);
        } else {
            unsigned short* ph = sel ? kh : qh;
            unsigned short* pl = sel ? kl : ql;
#pragma unroll
            for (int r = 0; r < 4; ++r) {
                float v = acc[ni][r] + bias;
                if (sel == 0) v *= scale;
                unsigned short hi = bf16_rn(v);
                int token = tb + r;
                int idx = token * HD + (dcol ^ (((token >> 1) & 3) << 3));
                ph[idx] = hi;
                pl[idx] = bf16_rn(v - bf16f(hi));
            }
        }
    }
    __syncthreads();

    // ================= Phase 2: S^T = K·Q^T, in-register softmax ============
    f32x4 sacc[8];
#pragma unroll
    for (int mi = 0; mi < 8; ++mi) sacc[mi] = (f32x4){0.f, 0.f, 0.f, 0.f};

    const int qrow = w * 16 + l15;
    const int qoff = qrow * HD + ((sct * 8) ^ (((qrow >> 1) & 3) << 3));
    bf16x8 qfh = *reinterpret_cast<const bf16x8*>(qh + qoff);
    bf16x8 qfl = *reinterpret_cast<const bf16x8*>(ql + qoff);
    __builtin_amdgcn_s_setprio(1);
#pragma unroll
    for (int mi = 0; mi < 8; ++mi) {
        int krow = (mi << 4) + l15;
        int off = krow * HD + ((sct * 8) ^ (((krow >> 1) & 3) << 3));
        bf16x8 kfh = *reinterpret_cast<const bf16x8*>(kh + off);
        bf16x8 kfl = *reinterpret_cast<const bf16x8*>(kl + off);
        sacc[mi] = __builtin_amdgcn_mfma_f32_16x16x32_bf16(kfh, qfh, sacc[mi], 0, 0, 0);
        sacc[mi] = __builtin_amdgcn_mfma_f32_16x16x32_bf16(kfh, qfl, sacc[mi], 0, 0, 0);
        sacc[mi] = __builtin_amdgcn_mfma_f32_16x16x32_bf16(kfl, qfh, sacc[mi], 0, 0, 0);
    }
    __builtin_amdgcn_s_setprio(0);
    // convert to ordered keys in place
#pragma unroll
    for (int mi = 0; mi < 8; ++mi)
#pragma unroll
        for (int r = 0; r < 4; ++r)
            sacc[mi][r] = __uint_as_float(okey(sacc[mi][r]));

    // row max and min (monotone in key domain)
    unsigned int km = 0u, kn = 0xFFFFFFFFu;
#pragma unroll
    for (int mi = 0; mi < 8; ++mi)
#pragma unroll
        for (int r = 0; r < 4; ++r) {
            unsigned int u = __float_as_uint(sacc[mi][r]);
            km = max(km, u);
            kn = min(kn, u);
        }
    km = max(km, (unsigned int)__shfl_xor((int)km, 16));
    km = max(km, (unsigned int)__shfl_xor((int)km, 32));
    kn = min(kn, (unsigned int)__shfl_xor((int)kn, 16));
    kn = min(kn, (unsigned int)__shfl_xor((int)kn, 32));
    float mx = okey_inv(km);

    // exact top-20 threshold: bracketed bisection from [kn, km+1], early exit
    unsigned p0;
    {
        unsigned lo = kn, hi = km + 1u, th = km;
        int dn = 0;
#pragma unroll 1
        for (int it = 0; it < 34; ++it) {
            if (__all(dn)) break;
            unsigned mid = lo + ((hi - lo) >> 1);
            int c = 0;
#pragma unroll
            for (int mi = 0; mi < 8; ++mi)
#pragma unroll
                for (int r = 0; r < 4; ++r)
                    c += (__float_as_uint(sacc[mi][r]) >= mid) ? 1 : 0;
            c += __shfl_xor(c, 16);
            c += __shfl_xor(c, 32);
            if (!dn) {
                if (c == TOPM) { th = mid; dn = 1; }
                else if (hi - lo <= 1u) { th = lo; dn = 1; }
                else if (c > TOPM) lo = mid;
                else hi = mid;
            }
        }
        p0 = th;
    }

    // masked exp (unnormalized) + row sum
    float s0 = 0.f;
#pragma unroll
    for (int mi = 0; mi < 8; ++mi)
#pragma unroll
        for (int r = 0; r < 4; ++r) {
            unsigned int u0 = __float_as_uint(sacc[mi][r]);
            float e0 = (u0 >= p0) ? __expf(okey_inv(u0) - mx) : 0.f;
            sacc[mi][r] = e0;
            s0 += e0;
        }
    s0 += __shfl_xor(s0, 16);
    s0 += __shfl_xor(s0, 32);
    float i0 = 1.f / s0;

    // pack weights to bf16 pairs
    unsigned w16a[8][2];
#pragma unroll
    for (int mi = 0; mi < 8; ++mi)
#pragma unroll
        for (int p = 0; p < 2; ++p)
            w16a[mi][p] = pk_bf16(sacc[mi][2 * p], sacc[mi][2 * p + 1]);

    // ================= Phase 3: O = P·V via MFMA ==============
    f32x4 oacc[2];
#pragma unroll
    for (int ni = 0; ni < 2; ++ni) oacc[ni] = (f32x4){0.f, 0.f, 0.f, 0.f};

#pragma unroll
    for (int k = 0; k < 4; ++k) {
        bf16x8 bvh[2];
#pragma unroll
        for (int nio = 0; nio < 2; ++nio) {
            int drow = (nio << 4) + l15;
            int off = drow * SEQN + ((k * 32 + sct * 8) ^ ((drow & 7) << 3));
            bvh[nio] = *reinterpret_cast<const bf16x8*>(vh + off);
        }
        union { unsigned u[4]; bf16x8 v8; } aw;
#pragma unroll
        for (int j = 0; j < 4; ++j) {
            int src = l15 + ((sct & 1) << 5) + ((j >> 1) << 4);
            unsigned a0 = (unsigned)__shfl((int)w16a[2 * k][j & 1], src);
            unsigned a1 = (unsigned)__shfl((int)w16a[2 * k + 1][j & 1], src);
            aw.u[j] = (sct >= 2) ? a1 : a0;
        }
        __builtin_amdgcn_s_setprio(1);
#pragma unroll
        for (int nio = 0; nio < 2; ++nio)
            oacc[nio] = __builtin_amdgcn_mfma_f32_16x16x32_bf16(aw.v8, bvh[nio], oacc[nio], 0, 0, 0);
        __builtin_amdgcn_s_setprio(0);
    }
    float invO[4];
#pragma unroll
    for (int r = 0; r < 4; ++r) invO[r] = __shfl(i0, sct * 4 + r);
#pragma unroll
    for (int nio = 0; nio < 2; ++nio)
#pragma unroll
        for (int r = 0; r < 4; ++r) {
            int token = w * 16 + sct * 4 + r;
            int d = (nio << 4) + l15;
            size_t idx = ((size_t)b * SEQN + token) * CDIM + h * HD + d;
            float v = oacc[nio][r] * invO[r];
            unsigned short hi = bf16_rn(v);
            OH[idx] = hi;
            OL[idx] = bf16_rn(v - bf16f(hi));
        }
}

// ---------------------------------------------------------------------------
// K3: MFMA proj GEMM + bias + residual + LayerNorm, 32 tokens per block.
// grid (480, 4), block 256 (4 waves, each 32 tok x 64 cols).  LDS ~39 KB.
__global__ __launch_bounds__(256, 4) void projln_kernel(
    const unsigned short* __restrict__ OHp, const unsigned short* __restrict__ OLp,
    unsigned short* __restrict__ XH, unsigned short* __restrict__ XL,
    const unsigned short* __restrict__ W2H, const unsigned short* __restrict__ W2L,
    const float* __restrict__ PB, const float* __restrict__ G,
    const float* __restrict__ BB) {
    const int b = blockIdx.x;
    const int t0 = blockIdx.y * 32;
    __shared__ float vals[32 * 289];
    __shared__ float part[8][32][2];

    const int tid = threadIdx.x;
    const int w = tid >> 6;
    const int l = tid & 63;
    const int l15 = l & 15;
    const int sct = l >> 4;

    f32x4 acc[2][4];
#pragma unroll
    for (int mi = 0; mi < 2; ++mi)
#pragma unroll
        for (int ni = 0; ni < 4; ++ni) acc[mi][ni] = (f32x4){0.f, 0.f, 0.f, 0.f};

    const size_t obase = ((size_t)b * SEQN + t0) * CDIM;
#pragma unroll 2
    for (int ks = 0; ks < 8; ++ks) {
        const int kb = ks * 32;
        bf16x8 ahi[2], alo[2];
#pragma unroll
        for (int mi = 0; mi < 2; ++mi) {
            size_t off = obase + (size_t)(mi * 16 + l15) * CDIM + kb + sct * 8;
            ahi[mi] = *reinterpret_cast<const bf16x8*>(OHp + off);
            alo[mi] = *reinterpret_cast<const bf16x8*>(OLp + off);
        }
#pragma unroll
        for (int ni = 0; ni < 4; ++ni) {
            int j = w * 64 + ni * 16 + l15;
            int woff = j * 256 + kb + sct * 8;
            bf16x8 bh = *reinterpret_cast<const bf16x8*>(W2H + woff);
            bf16x8 bl = *reinterpret_cast<const bf16x8*>(W2L + woff);
#pragma unroll
            for (int mi = 0; mi < 2; ++mi) {
                acc[mi][ni] = __builtin_amdgcn_mfma_f32_16x16x32_bf16(ahi[mi], bh, acc[mi][ni], 0, 0, 0);
                acc[mi][ni] = __builtin_amdgcn_mfma_f32_16x16x32_bf16(ahi[mi], bl, acc[mi][ni], 0, 0, 0);
                acc[mi][ni] = __builtin_amdgcn_mfma_f32_16x16x32_bf16(alo[mi], bh, acc[mi][ni], 0, 0, 0);
            }
        }
    }
    // bias + stage to LDS (stride 289 -> conflict-free strided readback)
#pragma unroll
    for (int ni = 0; ni < 4; ++ni) {
        int j = w * 64 + ni * 16 + l15;
        float bias = PB[j];
#pragma unroll
        for (int mi = 0; mi < 2; ++mi)
#pragma unroll
            for (int r = 0; r < 4; ++r) {
                int tok = mi * 16 + sct * 4 + r;
                vals[tok * 289 + j] = acc[mi][ni][r] + bias;
            }
    }
    __syncthreads();

    // residual + stats: thread = (row 0..31, cc 0..7 chunks of 32 cols)
    const int row = tid & 31;
    const int cc = tid >> 5;
    const size_t rbase = ((size_t)b * SEQN + t0 + row) * CDIM + cc * 32;
    float v[32];
    {
        float ps = 0.f, pq = 0.f;
#pragma unroll
        for (int q = 0; q < 4; ++q) {
            uint4 hb = *reinterpret_cast<const uint4*>(XH + rbase + q * 8);
            uint4 lb = *reinterpret_cast<const uint4*>(XL + rbase + q * 8);
            float rh[8], rl[8];
            unpack_bf16x8(hb, rh);
            unpack_bf16x8(lb, rl);
#pragma unroll
            for (int jj = 0; jj < 8; ++jj) {
                int col = cc * 32 + q * 8 + jj;
                float val = vals[row * 289 + col] + rh[jj] + rl[jj];
                v[q * 8 + jj] = val;
                ps += val;
                pq = fmaf(val, val, pq);
            }
        }
        part[cc][row][0] = ps;
        part[cc][row][1] = pq;
    }
    __syncthreads();
    float s1 = 0.f, s2 = 0.f;
#pragma unroll
    for (int k = 0; k < 8; ++k) { s1 += part[k][row][0]; s2 += part[k][row][1]; }
    float m = s1 * (1.f / 256.f);
    float var = s2 * (1.f / 256.f) - m * m;
    float rstd = rsqrtf(var + 1e-5f);
#pragma unroll
    for (int q = 0; q < 4; ++q) {
        int col0 = cc * 32 + q * 8;
        float4 g0 = *reinterpret_cast<const float4*>(G + col0);
        float4 g1 = *reinterpret_cast<const float4*>(G + col0 + 4);
        float4 b0 = *reinterpret_cast<const float4*>(BB + col0);
        float4 b1 = *reinterpret_cast<const float4*>(BB + col0 + 4);
        float gg[8] = {g0.x, g0.y, g0.z, g0.w, g1.x, g1.y, g1.z, g1.w};
        float bb2[8] = {b0.x, b0.y, b0.z, b0.w, b1.x, b1.y, b1.z, b1.w};
        unsigned hw[4], lw[4];
#pragma unroll
        for (int p2 = 0; p2 < 4; ++p2) {
            float y0 = (v[q * 8 + p2 * 2] - m) * rstd * gg[p2 * 2] + bb2[p2 * 2];
            float y1 = (v[q * 8 + p2 * 2 + 1] - m) * rstd * gg[p2 * 2 + 1] + bb2[p2 * 2 + 1];
            unsigned short h0 = bf16_rn(y0), h1 = bf16_rn(y1);
            unsigned short lo0 = bf16_rn(y0 - bf16f(h0)), lo1 = bf16_rn(y1 - bf16f(h1));
            hw[p2] = (unsigned)h0 | ((unsigned)h1 << 16);
            lw[p2] = (unsigned)lo0 | ((unsigned)lo1 << 16);
        }
        *reinterpret_cast<uint4*>(XH + rbase + q * 8) = make_uint4(hw[0], hw[1], hw[2], hw[3]);
        *reinterpret_cast<uint4*>(XL + rbase + q * 8) = make_uint4(lw[0], lw[1], lw[2], lw[3]);
    }
}

// ---------------------------------------------------------------------------
// K4: mean over tokens + classifier head (reads planes). grid 480, block 256.
__global__ __launch_bounds__(256) void cls_kernel(const unsigned short* __restrict__ XH,
                                                  const unsigned short* __restrict__ XL,
                                                  const float* __restrict__ W1,
                                                  const float* __restrict__ B1,
                                                  const float* __restrict__ W2,
                                                  const float* __restrict__ B2,
                                                  float* __restrict__ OUT) {
    int b = blockIdx.x;
    __shared__ float xm[256];
    __shared__ float hred[128];
    int tid = threadIdx.x;
    float sm = 0.f;
    for (int n = 0; n < SEQN; ++n) {
        size_t idx = ((size_t)b * SEQN + n) * CDIM + tid;
        sm += bf16f(XH[idx]) + bf16f(XL[idx]);
    }
    xm[tid] = sm * (1.f / 128.f);
    __syncthreads();
    if (tid < 128) {
        float a = B1[tid];
        for (int k = 0; k < CDIM; ++k) a = fmaf(xm[k], W1[k * 128 + tid], a);
        a = fmaxf(a, 0.f);
        hred[tid] = a * W2[tid];
    }
    __syncthreads();
    for (int off = 64; off > 0; off >>= 1) {
        if (tid < off) hred[tid] += hred[tid + off];
        __syncthreads();
    }
    if (tid == 0) OUT[b] = hred[0] + B2[0];
}

// ---------------------------------------------------------------------------
extern "C" void kernel_launch(void* const* d_in, const int* in_sizes, int n_in,
                              void* d_out, int out_size, void* d_ws, size_t ws_size,
                              hipStream_t stream) {
    const float* RW  = (const float*)d_in[0];
    const float* POS = (const float*)d_in[1];
    const float* CW1 = (const float*)d_in[2];
    const float* CB1 = (const float*)d_in[3];
    const float* CW2 = (const float*)d_in[4];
    const float* CB2 = (const float*)d_in[5];

    const size_t NTOK = (size_t)NSEQ * SEQN * CDIM;  // 15.7M
    unsigned short* OH = (unsigned short*)d_ws;
    unsigned short* OL = OH + NTOK;
    unsigned short* XH = OL + NTOK;
    unsigned short* XL = XH + NTOK;
    unsigned short* WtHi = XL + NTOK;
    unsigned short* WtLo = WtHi + (size_t)768 * 256;
    unsigned short* W2H = WtLo + (size_t)768 * 256;
    unsigned short* W2L = W2H + (size_t)256 * 256;

    prep_kernel<<<dim3(NSEQ, 4, 8), 256, 0, stream>>>(RW, POS, XH, XL);

    for (int li = 0; li < 2; ++li) {
        const float* qw = (const float*)d_in[6 + 6 * li];
        const float* qb = (const float*)d_in[7 + 6 * li];
        const float* pw = (const float*)d_in[8 + 6 * li];
        const float* pb = (const float*)d_in[9 + 6 * li];
        const float* lg = (const float*)d_in[10 + 6 * li];
        const float* lb = (const float*)d_in[11 + 6 * li];
        wsplit2_kernel<<<dim3(8, 32), 256, 0, stream>>>(qw, pw, WtHi, WtLo, W2H, W2L);
        attn_kernel<<<NSEQ * NH, 512, 0, stream>>>(XH, XL, OH, OL, WtHi, WtLo, qb);
        projln_kernel<<<dim3(NSEQ, 4), 256, 0, stream>>>(OH, OL, XH, XL, W2H, W2L, pb, lg, lb);
    }

    cls_kernel<<<NSEQ, 256, 0, stream>>>(XH, XL, CW1, CB1, CW2, CB2, (float*)d_out);
}